// Round 6
// baseline (251.777 us; speedup 1.0000x reference)
//
#include <hip/hip_runtime.h>

#define NBROWS 32768
#define ND 1024
#define NT 16
#define NC 1000
#define NHB 128
#define KT 16
#define MAX_RB128 272

typedef short short8 __attribute__((ext_vector_type(8)));
typedef float f32x4 __attribute__((ext_vector_type(4)));
typedef unsigned short ushort_t;

typedef __attribute__((address_space(1))) const unsigned int* gas_t;
typedef __attribute__((address_space(3))) unsigned int* las_t;

__device__ __forceinline__ void async_copy16(const void* g, void* l) {
  __builtin_amdgcn_global_load_lds((gas_t)g, (las_t)l, 16, 0, 0);
}

__device__ __forceinline__ unsigned f2bf(float f) {
  unsigned u = __float_as_uint(f);
  u += 0x7FFFu + ((u >> 16) & 1u);  // round-nearest-even
  return u >> 16;
}
__device__ __forceinline__ unsigned pk2(float a, float b) {
  return f2bf(a) | (f2bf(b) << 16);
}
__device__ __forceinline__ int swz(int row) { return (row & 3) ^ ((row >> 2) & 3); }

// ---------------- fused scores + W-conversion ----------------
__global__ __launch_bounds__(512) void fused_pre(
    const float* __restrict__ x, const float* __restrict__ sigs_raw,
    int* __restrict__ tidx, float* __restrict__ out_idx,
    const float* __restrict__ W, ushort_t* __restrict__ wbf) {
  __shared__ signed char s_lds[NT * ND];
  int tid = threadIdx.x;
  int bid = blockIdx.x;
  if (bid >= 4096) {
    if (!wbf) return;
    size_t e = (((size_t)(bid - 4096)) * 512 + tid) * 8;
    int t = (int)(e >> 20);
    int rem = (int)(e & 1048575);
    int col = rem >> 10, k = rem & 1023;
    uint4 o;
    if (col < NC) {
      const float* src = W + ((size_t)t * NC + col) * ND + k;
      float4 a = *(const float4*)src;
      float4 b = *(const float4*)(src + 4);
      o = make_uint4(pk2(a.x, a.y), pk2(a.z, a.w), pk2(b.x, b.y), pk2(b.z, b.w));
    } else {
      o = make_uint4(0, 0, 0, 0);
    }
    *(uint4*)(wbf + e) = o;
    return;
  }
  for (int i = tid; i < NT * ND; i += 512) {
    float s = sigs_raw[i];
    s_lds[i] = (s > 0.3f) ? 1 : ((s < -0.3f) ? -1 : 0);
  }
  __syncthreads();
  int lane = tid & 63;
  int row = bid * 8 + (tid >> 6);
  const float* xr = x + (size_t)row * ND + lane * 16;
  float4 v0 = *(const float4*)(xr);
  float4 v1 = *(const float4*)(xr + 4);
  float4 v2 = *(const float4*)(xr + 8);
  float4 v3 = *(const float4*)(xr + 12);
  float xv[16] = {v0.x, v0.y, v0.z, v0.w, v1.x, v1.y, v1.z, v1.w,
                  v2.x, v2.y, v2.z, v2.w, v3.x, v3.y, v3.z, v3.w};
  float best = 0.0f;
  int bt = 0;
#pragma unroll
  for (int t = 0; t < NT; t++) {
    int4 sc = *(const int4*)(s_lds + t * ND + lane * 16);
    int wa[4] = {sc.x, sc.y, sc.z, sc.w};
    float p = 0.0f;
#pragma unroll
    for (int wi = 0; wi < 4; wi++)
#pragma unroll
      for (int bi = 0; bi < 4; bi++)
        p = fmaf((float)(signed char)(wa[wi] >> (8 * bi)), xv[wi * 4 + bi], p);
#pragma unroll
    for (int o = 32; o > 0; o >>= 1) p += __shfl_xor(p, o);
    if (t == 0 || p > best) { best = p; bt = t; }  // strict >: first index on tie (jnp.argmax)
  }
  if (lane == 0) {
    tidx[row] = bt;
    out_idx[row] = (float)bt;
  }
}

// ---------------- histogram / prefix / scatter (no global atomics) ----------------
__global__ __launch_bounds__(256) void trix_hist(const int* __restrict__ tidx,
                                                 int* __restrict__ blkhist) {
  __shared__ int h[NT];
  int tid = threadIdx.x;
  if (tid < NT) h[tid] = 0;
  __syncthreads();
  int t = tidx[blockIdx.x * 256 + tid];
  atomicAdd(&h[t], 1);
  __syncthreads();
  if (tid < NT) blkhist[blockIdx.x * NT + tid] = h[tid];
}

// meta: [0..15] counts, [16..32] row offsets, [33..49] cb256 (49=total), [50..66] cb128 (66=total)
__global__ __launch_bounds__(256) void trix_prefix(const int* __restrict__ blkhist,
                                                   int* __restrict__ blkbase,
                                                   int* __restrict__ meta) {
  __shared__ int part[NT][16];
  int tid = threadIdx.x;
  int t = tid >> 4, g = tid & 15;
  int s = 0;
  for (int b = g; b < NHB; b += 16) s += blkhist[b * NT + t];
  part[t][g] = s;
  __syncthreads();
  if (tid == 0) {
    int off = 0, cb = 0, cb2 = 0;
    for (int tt = 0; tt < NT; tt++) {
      int c = 0;
#pragma unroll
      for (int gg = 0; gg < 16; gg++) c += part[tt][gg];
      meta[tt] = c;
      meta[16 + tt] = off;
      meta[33 + tt] = cb;
      meta[50 + tt] = cb2;
      off += c;
      cb += (c + 255) >> 8;
      cb2 += (c + 127) >> 7;
    }
    meta[32] = off;
    meta[49] = cb;
    meta[66] = cb2;
  }
  __syncthreads();
  if (tid < NT) {
    int run = meta[16 + tid];
    for (int b = 0; b < NHB; b++) {
      blkbase[b * NT + tid] = run;
      run += blkhist[b * NT + tid];
    }
  }
}

__global__ __launch_bounds__(256) void trix_scatter(const int* __restrict__ tidx,
                                                    const int* __restrict__ blkbase,
                                                    int* __restrict__ rowlist) {
  __shared__ int h[NT];
  int tid = threadIdx.x;
  if (tid < NT) h[tid] = 0;
  __syncthreads();
  int row = blockIdx.x * 256 + tid;
  int t = tidx[row];
  int r = atomicAdd(&h[t], 1);
  rowlist[blkbase[blockIdx.x * NT + t] + r] = row;
}

// ---------------- gather: xsrt[p] = bf16(x[rowlist[p]]) (linear A for GEMM) ----------------
__global__ __launch_bounds__(512) void trix_gather(const float* __restrict__ x,
                                                   const int* __restrict__ rowlist,
                                                   ushort_t* __restrict__ xsrt) {
  int tid = threadIdx.x;
  int lane = tid & 63, wv = tid >> 6;
  int p = blockIdx.x * 8 + wv;
  int row = rowlist[p];
  const float* src = x + (size_t)row * ND + lane * 16;
  float4 v0 = *(const float4*)(src);
  float4 v1 = *(const float4*)(src + 4);
  float4 v2 = *(const float4*)(src + 8);
  float4 v3 = *(const float4*)(src + 12);
  ushort_t* dst = xsrt + (size_t)p * ND + lane * 16;
  *(uint4*)(dst) = make_uint4(pk2(v0.x, v0.y), pk2(v0.z, v0.w), pk2(v1.x, v1.y), pk2(v1.z, v1.w));
  *(uint4*)(dst + 8) = make_uint4(pk2(v2.x, v2.y), pk2(v2.z, v2.w), pk2(v3.x, v3.y), pk2(v3.z, v3.w));
}

// ---------------- 8-phase 256x256 GEMM (T2+T3+T4+T5), linear sorted A ----------------
__global__ __launch_bounds__(512, 2) void trix_gemm3(
    const ushort_t* __restrict__ xsrt, const ushort_t* __restrict__ wbf,
    const float* __restrict__ bias, const int* __restrict__ meta,
    const int* __restrict__ rowlist, float* __restrict__ out) {
  __shared__ __align__(16) ushort_t Ab[2][2][8192];   // [dbuf][half][128 rows x 64 k]
  __shared__ __align__(16) ushort_t Bb[2][2][8192];
  __shared__ int rl[256];
  __shared__ __align__(16) ushort_t dmy[512];
  int bid = blockIdx.x;
  int w = (bid & 7) * 72 + (bid >> 3);  // bijective XCD chunk swizzle (576 = 8*72)
  int nb = w / 144, rb = w % 144;
  if (rb >= meta[49]) return;
  int t = 0;
  while (t < NT - 1 && rb >= meta[34 + t]) t++;
  int row0 = meta[16 + t] + (rb - meta[33 + t]) * 256;
  int cnt = meta[17 + t] - row0;
  if (cnt > 256) cnt = 256;
  int tid = threadIdx.x;
  if (tid < 256) rl[tid] = rowlist[(tid < cnt) ? (row0 + tid) : row0];

  int lane = tid & 63, wv = tid >> 6;
  int wr = wv >> 2, wc = wv & 3;          // 2M x 4N waves; per-wave 128x64 output
  int rsel = lane & 15, ksl = lane >> 4, rx = rsel & 7;

  // staging: wave wv, inst i covers rows (wv*2+i)*8 + (lane>>3); source slot pre-swizzled
  int srow = lane >> 3;
  int schunk = ((lane & 7) ^ srow) * 8;   // element offset of 16B chunk
  const ushort_t* aBase = xsrt + (size_t)row0 * ND;   // uniform (SGPR) base
  int aL0 = (wv * 16 + srow) * ND + schunk;           // half0 rows
  int aL1 = (wv * 16 + 8 + srow) * ND + schunk;
  int aH0 = aL0 + 128 * ND;                           // half1 rows
  int aH1 = aL1 + 128 * ND;
  int bO0 = (t << 20) + (nb * 256 + wv * 16 + srow) * ND + schunk;
  int bO1 = bO0 + 8 * ND;

  ushort_t* AbM = &Ab[0][0][0];
  ushort_t* BbM = &Bb[0][0][0];
  const ushort_t* Af = AbM;
  const ushort_t* Bf = BbM;
  int aro = wr * 8192 + rsel * 64;                       // + db*16384 + m*1024 + slot
  int bro = (wc >> 1) * 8192 + (wc & 1) * 4096 + rsel * 64;
  int sl0 = ((0 * 4 + ksl) ^ rx) * 8;
  int sl1 = ((1 * 4 + ksl) ^ rx) * 8;

  short8 af[4][2], bfA[2][2], bfB[2][2];
  f32x4 acc[8][4] = {};

#define SA(DB1, H, KTL) { \
    ushort_t* d_ = AbM + ((DB1) * 2 + (H)) * 8192 + wv * 1024; \
    async_copy16(aBase + ((H) ? aH0 : aL0) + (KTL) * 64, d_); \
    async_copy16(aBase + ((H) ? aH1 : aL1) + (KTL) * 64, d_ + 512); }
#define SB(DB1, H, KTL) { \
    ushort_t* d_ = BbM + ((DB1) * 2 + (H)) * 8192 + wv * 1024; \
    async_copy16(wbf + bO0 + (H) * (128 * ND) + (KTL) * 64, d_); \
    async_copy16(wbf + bO1 + (H) * (128 * ND) + (KTL) * 64, d_ + 512); }
#define SDM { async_copy16(xsrt + lane * 8, dmy); async_copy16(xsrt + lane * 8, dmy); }

#define LD_A(DBO, MB) \
    af[0][0] = *(const short8*)(Af + (DBO) + aro + ((MB) + 0) * 1024 + sl0); \
    af[0][1] = *(const short8*)(Af + (DBO) + aro + ((MB) + 0) * 1024 + sl1); \
    af[1][0] = *(const short8*)(Af + (DBO) + aro + ((MB) + 1) * 1024 + sl0); \
    af[1][1] = *(const short8*)(Af + (DBO) + aro + ((MB) + 1) * 1024 + sl1); \
    af[2][0] = *(const short8*)(Af + (DBO) + aro + ((MB) + 2) * 1024 + sl0); \
    af[2][1] = *(const short8*)(Af + (DBO) + aro + ((MB) + 2) * 1024 + sl1); \
    af[3][0] = *(const short8*)(Af + (DBO) + aro + ((MB) + 3) * 1024 + sl0); \
    af[3][1] = *(const short8*)(Af + (DBO) + aro + ((MB) + 3) * 1024 + sl1);
#define LD_B(DBO, NB0, dst) \
    dst[0][0] = *(const short8*)(Bf + (DBO) + bro + ((NB0) + 0) * 1024 + sl0); \
    dst[0][1] = *(const short8*)(Bf + (DBO) + bro + ((NB0) + 0) * 1024 + sl1); \
    dst[1][0] = *(const short8*)(Bf + (DBO) + bro + ((NB0) + 1) * 1024 + sl0); \
    dst[1][1] = *(const short8*)(Bf + (DBO) + bro + ((NB0) + 1) * 1024 + sl1);

#define MM16(MB, NB0, bsrc) \
    _Pragma("unroll") for (int m_ = 0; m_ < 4; ++m_) \
    _Pragma("unroll") for (int n_ = 0; n_ < 2; ++n_) \
    _Pragma("unroll") for (int k_ = 0; k_ < 2; ++k_) \
      acc[(MB) + m_][(NB0) + n_] = __builtin_amdgcn_mfma_f32_16x16x32_bf16( \
          af[m_][k_], bsrc[n_][k_], acc[(MB) + m_][(NB0) + n_], 0, 0, 0);

#define PH(BODY) \
    __builtin_amdgcn_s_barrier(); \
    asm volatile("s_waitcnt lgkmcnt(0)" ::: "memory"); \
    __builtin_amdgcn_s_setprio(1); \
    BODY; \
    __builtin_amdgcn_s_setprio(0); \
    __builtin_amdgcn_s_barrier();
#define PH12(BODY) \
    asm volatile("s_waitcnt lgkmcnt(8)" ::: "memory"); \
    __builtin_amdgcn_s_barrier(); \
    asm volatile("s_waitcnt lgkmcnt(0)" ::: "memory"); \
    __builtin_amdgcn_s_setprio(1); \
    BODY; \
    __builtin_amdgcn_s_setprio(0); \
    __builtin_amdgcn_s_barrier();
#define PH_LAST(BODY) \
    __builtin_amdgcn_s_barrier(); \
    asm volatile("s_waitcnt lgkmcnt(0)" ::: "memory"); \
    __builtin_amdgcn_s_setprio(1); \
    BODY; \
    __builtin_amdgcn_s_setprio(0); \
    asm volatile("s_waitcnt vmcnt(4)" ::: "memory"); \
    __builtin_amdgcn_s_barrier();

#define TILE(T, DB) { \
    const int dbo_ = (DB) * 16384; \
    LD_A(dbo_, 0); LD_B(dbo_, 0, bfA); \
    if ((T) + 1 < KT) { SA((DB) ^ 1, 0, (T) + 1); } else { SDM; } \
    PH12(MM16(0, 0, bfA)); \
    LD_B(dbo_, 2, bfB); \
    if ((T) + 1 < KT) { SA((DB) ^ 1, 1, (T) + 1); } else { SDM; } \
    PH(MM16(0, 2, bfB)); \
    LD_A(dbo_, 4); \
    if ((T) + 2 < KT) { SB(DB, 0, (T) + 2); } else { SDM; } \
    PH(MM16(4, 0, bfA)); \
    if ((T) + 2 < KT) { SB(DB, 1, (T) + 2); } else { SDM; } \
    PH_LAST(MM16(4, 2, bfB)); \
  }

  // prologue: A(0), B(0) into dbuf0; B(1) into dbuf1; certify first 8, keep 4 in flight
  SA(0, 0, 0); SA(0, 1, 0); SB(0, 0, 0); SB(0, 1, 0); SB(1, 0, 1); SB(1, 1, 1);
  asm volatile("s_waitcnt vmcnt(4)" ::: "memory");
  __builtin_amdgcn_s_barrier();

#pragma unroll 1
  for (int tp = 0; tp < KT / 2; ++tp) {
    int T0 = tp * 2;
    TILE(T0, 0);
    TILE(T0 + 1, 1);
  }

  // epilogue: C/D layout col=lane&15, row=(lane>>4)*4+reg
  float bv[4];
  int bcol[4];
#pragma unroll
  for (int n = 0; n < 4; ++n) {
    bcol[n] = nb * 256 + wc * 64 + n * 16 + rsel;
    bv[n] = (bcol[n] < NC) ? bias[t * NC + bcol[n]] : 0.0f;
  }
#pragma unroll
  for (int m = 0; m < 8; ++m) {
#pragma unroll
    for (int r = 0; r < 4; ++r) {
      int lr = wr * 128 + m * 16 + ksl * 4 + r;
      if (lr < cnt) {
        size_t ob = (size_t)rl[lr] * NC;
#pragma unroll
        for (int n = 0; n < 4; ++n)
          if (bcol[n] < NC) out[ob + bcol[n]] = acc[m][n][r] + bv[n];
      }
    }
  }
}

// ---------------- fallback GEMM (f32 inputs, in-loop repack), cb128 meta ----------------
__global__ __launch_bounds__(256) void trix_gemm_fb(
    const float* __restrict__ x, const float* __restrict__ W,
    const float* __restrict__ bias, const int* __restrict__ meta,
    const int* __restrict__ rowlist, float* __restrict__ out) {
  __shared__ __align__(16) unsigned char aT[128 * 64];
  __shared__ __align__(16) unsigned char bT[128 * 64];
  __shared__ int rl[128];
  int nb = blockIdx.x, rb = blockIdx.y;
  if (rb >= meta[66]) return;
  int t = 0;
  while (t < NT - 1 && rb >= meta[51 + t]) t++;
  int row0 = meta[16 + t] + (rb - meta[50 + t]) * 128;
  int cnt = meta[17 + t] - row0;
  if (cnt > 128) cnt = 128;
  int tid = threadIdx.x;
  if (tid < 128) rl[tid] = rowlist[(tid < cnt) ? (row0 + tid) : row0];
  __syncthreads();
  int half = tid & 1, rloc = tid >> 1;
  const float* xp = x + (size_t)rl[rloc] * ND + half * 16;
  int wn = nb * 128 + rloc;
  if (wn > NC - 1) wn = NC - 1;
  const float* wp = W + ((size_t)t * NC + wn) * ND + half * 16;
  int sw = swz(rloc);
  unsigned char* aw0 = aT + rloc * 64 + (((half * 2 + 0) ^ sw) << 4);
  unsigned char* aw1 = aT + rloc * 64 + (((half * 2 + 1) ^ sw) << 4);
  unsigned char* bw0 = bT + rloc * 64 + (((half * 2 + 0) ^ sw) << 4);
  unsigned char* bw1 = bT + rloc * 64 + (((half * 2 + 1) ^ sw) << 4);
  int lane = tid & 63, wv = tid >> 6;
  int wr = wv >> 1, wc = wv & 1;
  int rsel = lane & 15, slot = lane >> 4;
  f32x4 acc[4][4] = {};
  for (int k0 = 0; k0 < ND; k0 += 32) {
    const float* xk = xp + k0;
    const float* wk = wp + k0;
    float4 a0 = *(const float4*)(xk);
    float4 a1 = *(const float4*)(xk + 4);
    float4 a2 = *(const float4*)(xk + 8);
    float4 a3 = *(const float4*)(xk + 12);
    float4 b0 = *(const float4*)(wk);
    float4 b1 = *(const float4*)(wk + 4);
    float4 b2 = *(const float4*)(wk + 8);
    float4 b3 = *(const float4*)(wk + 12);
    *(uint4*)aw0 = make_uint4(pk2(a0.x, a0.y), pk2(a0.z, a0.w), pk2(a1.x, a1.y), pk2(a1.z, a1.w));
    *(uint4*)aw1 = make_uint4(pk2(a2.x, a2.y), pk2(a2.z, a2.w), pk2(a3.x, a3.y), pk2(a3.z, a3.w));
    *(uint4*)bw0 = make_uint4(pk2(b0.x, b0.y), pk2(b0.z, b0.w), pk2(b1.x, b1.y), pk2(b1.z, b1.w));
    *(uint4*)bw1 = make_uint4(pk2(b2.x, b2.y), pk2(b2.z, b2.w), pk2(b3.x, b3.y), pk2(b3.z, b3.w));
    __syncthreads();
    short8 af2[4], bfr[4];
#pragma unroll
    for (int i = 0; i < 4; i++) {
      int arr = wr * 64 + i * 16 + rsel;
      af2[i] = *(const short8*)(aT + arr * 64 + ((slot ^ swz(arr)) << 4));
      int brr = wc * 64 + i * 16 + rsel;
      bfr[i] = *(const short8*)(bT + brr * 64 + ((slot ^ swz(brr)) << 4));
    }
#pragma unroll
    for (int mi = 0; mi < 4; mi++)
#pragma unroll
      for (int ni = 0; ni < 4; ni++)
        acc[mi][ni] = __builtin_amdgcn_mfma_f32_16x16x32_bf16(af2[mi], bfr[ni], acc[mi][ni], 0, 0, 0);
    __syncthreads();
  }
#pragma unroll
  for (int mi = 0; mi < 4; mi++) {
#pragma unroll
    for (int r = 0; r < 4; r++) {
      int rloc2 = wr * 64 + mi * 16 + slot * 4 + r;
      if (rloc2 < cnt) {
        size_t obase = (size_t)rl[rloc2] * NC;
#pragma unroll
        for (int ni = 0; ni < 4; ni++) {
          int col = nb * 128 + wc * 64 + ni * 16 + rsel;
          if (col < NC) out[obase + col] = acc[mi][ni][r] + bias[t * NC + col];
        }
      }
    }
  }
}

extern "C" void kernel_launch(void* const* d_in, const int* in_sizes, int n_in,
                              void* d_out, int out_size, void* d_ws, size_t ws_size,
                              hipStream_t stream) {
  const float* x = (const float*)d_in[0];
  const float* sigs = (const float*)d_in[1];
  const float* W = (const float*)d_in[2];
  const float* bias = (const float*)d_in[3];
  float* out = (float*)d_out;

  const size_t XSRT_B = (size_t)(NBROWS + 256) * ND * 2;  // sorted bf16 A (+pad rows)
  const size_t WBF_B = (size_t)NT * 1024 * ND * 2;        // 33,554,432
  bool fast = ws_size >= XSRT_B + WBF_B + (1 << 20);

  char* wsb = (char*)d_ws;
  ushort_t* xsrt = nullptr;
  ushort_t* wbf = nullptr;
  int* tidx;
  if (fast) {
    xsrt = (ushort_t*)wsb;
    wbf = (ushort_t*)(wsb + XSRT_B);
    tidx = (int*)(wsb + XSRT_B + WBF_B);
  } else {
    tidx = (int*)wsb;
  }
  int* rowlist = tidx + NBROWS;
  int* meta = rowlist + NBROWS;
  int* blkhist = meta + 80;
  int* blkbase = blkhist + NHB * NT;

  fused_pre<<<8192, 512, 0, stream>>>(x, sigs, tidx, out + (size_t)NBROWS * NC, W, wbf);
  trix_hist<<<NHB, 256, 0, stream>>>(tidx, blkhist);
  trix_prefix<<<1, 256, 0, stream>>>(blkhist, blkbase, meta);
  trix_scatter<<<NHB, 256, 0, stream>>>(tidx, blkbase, rowlist);
  if (fast) {
    trix_gather<<<NBROWS / 8, 512, 0, stream>>>(x, rowlist, xsrt);
    trix_gemm3<<<576, 512, 0, stream>>>(xsrt, wbf, bias, meta, rowlist, out);
  } else {
    trix_gemm_fb<<<dim3(8, MAX_RB128), 256, 0, stream>>>(x, W, bias, meta, rowlist, out);
  }
}

// Round 7
// 218.769 us; speedup vs baseline: 1.1509x; 1.1509x over previous
//
#include <hip/hip_runtime.h>

#define NBROWS 32768
#define ND 1024
#define NT 16
#define NC 1000
#define NHB 128
#define MAX_RB128 272  // worst-case 128-row blocks: 32768/128 + 16

typedef short short8 __attribute__((ext_vector_type(8)));
typedef float f32x4 __attribute__((ext_vector_type(4)));
typedef unsigned short ushort_t;

typedef __attribute__((address_space(1))) const unsigned int* gas_t;
typedef __attribute__((address_space(3))) unsigned int* las_t;

__device__ __forceinline__ void async_copy16(const void* g, void* l) {
  __builtin_amdgcn_global_load_lds((gas_t)g, (las_t)l, 16, 0, 0);
}

__device__ __forceinline__ unsigned f2bf(float f) {
  unsigned u = __float_as_uint(f);
  u += 0x7FFFu + ((u >> 16) & 1u);  // round-nearest-even
  return u >> 16;
}
__device__ __forceinline__ unsigned pk2(float a, float b) {
  return f2bf(a) | (f2bf(b) << 16);
}
__device__ __forceinline__ int swz(int row) { return (row & 3) ^ ((row >> 2) & 3); }

// ---------------- fused scores + W-conversion ----------------
__global__ __launch_bounds__(512) void fused_pre(
    const float* __restrict__ x, const float* __restrict__ sigs_raw,
    int* __restrict__ tidx, float* __restrict__ out_idx,
    const float* __restrict__ W, ushort_t* __restrict__ wbf) {
  __shared__ signed char s_lds[NT * ND];
  int tid = threadIdx.x;
  int bid = blockIdx.x;
  if (bid >= 4096) {
    if (!wbf) return;
    size_t e = (((size_t)(bid - 4096)) * 512 + tid) * 8;
    int t = (int)(e >> 20);
    int rem = (int)(e & 1048575);
    int col = rem >> 10, k = rem & 1023;
    uint4 o;
    if (col < NC) {
      const float* src = W + ((size_t)t * NC + col) * ND + k;
      float4 a = *(const float4*)src;
      float4 b = *(const float4*)(src + 4);
      o = make_uint4(pk2(a.x, a.y), pk2(a.z, a.w), pk2(b.x, b.y), pk2(b.z, b.w));
    } else {
      o = make_uint4(0, 0, 0, 0);
    }
    *(uint4*)(wbf + e) = o;
    return;
  }
  for (int i = tid; i < NT * ND; i += 512) {
    float s = sigs_raw[i];
    s_lds[i] = (s > 0.3f) ? 1 : ((s < -0.3f) ? -1 : 0);
  }
  __syncthreads();
  int lane = tid & 63;
  int row = bid * 8 + (tid >> 6);
  const float* xr = x + (size_t)row * ND + lane * 16;
  float4 v0 = *(const float4*)(xr);
  float4 v1 = *(const float4*)(xr + 4);
  float4 v2 = *(const float4*)(xr + 8);
  float4 v3 = *(const float4*)(xr + 12);
  float xv[16] = {v0.x, v0.y, v0.z, v0.w, v1.x, v1.y, v1.z, v1.w,
                  v2.x, v2.y, v2.z, v2.w, v3.x, v3.y, v3.z, v3.w};
  float best = 0.0f;
  int bt = 0;
#pragma unroll
  for (int t = 0; t < NT; t++) {
    int4 sc = *(const int4*)(s_lds + t * ND + lane * 16);
    int wa[4] = {sc.x, sc.y, sc.z, sc.w};
    float p = 0.0f;
#pragma unroll
    for (int wi = 0; wi < 4; wi++)
#pragma unroll
      for (int bi = 0; bi < 4; bi++)
        p = fmaf((float)(signed char)(wa[wi] >> (8 * bi)), xv[wi * 4 + bi], p);
#pragma unroll
    for (int o = 32; o > 0; o >>= 1) p += __shfl_xor(p, o);
    if (t == 0 || p > best) { best = p; bt = t; }  // strict >: first index on tie (jnp.argmax)
  }
  if (lane == 0) {
    tidx[row] = bt;
    out_idx[row] = (float)bt;
  }
}

// ---------------- histogram / prefix / scatter (no global atomics) ----------------
__global__ __launch_bounds__(256) void trix_hist(const int* __restrict__ tidx,
                                                 int* __restrict__ blkhist) {
  __shared__ int h[NT];
  int tid = threadIdx.x;
  if (tid < NT) h[tid] = 0;
  __syncthreads();
  int t = tidx[blockIdx.x * 256 + tid];
  atomicAdd(&h[t], 1);
  __syncthreads();
  if (tid < NT) blkhist[blockIdx.x * NT + tid] = h[tid];
}

// meta: [0..15] counts, [16..32] row offsets, [50..66] cb128 (66=total)
__global__ __launch_bounds__(256) void trix_prefix(const int* __restrict__ blkhist,
                                                   int* __restrict__ blkbase,
                                                   int* __restrict__ meta) {
  __shared__ int part[NT][16];
  int tid = threadIdx.x;
  int t = tid >> 4, g = tid & 15;
  int s = 0;
  for (int b = g; b < NHB; b += 16) s += blkhist[b * NT + t];
  part[t][g] = s;
  __syncthreads();
  if (tid == 0) {
    int off = 0, cb2 = 0;
    for (int tt = 0; tt < NT; tt++) {
      int c = 0;
#pragma unroll
      for (int gg = 0; gg < 16; gg++) c += part[tt][gg];
      meta[tt] = c;
      meta[16 + tt] = off;
      meta[50 + tt] = cb2;
      off += c;
      cb2 += (c + 127) >> 7;
    }
    meta[32] = off;
    meta[66] = cb2;
  }
  __syncthreads();
  if (tid < NT) {
    int run = meta[16 + tid];
    for (int b = 0; b < NHB; b++) {
      blkbase[b * NT + tid] = run;
      run += blkhist[b * NT + tid];
    }
  }
}

__global__ __launch_bounds__(256) void trix_scatter(const int* __restrict__ tidx,
                                                    const int* __restrict__ blkbase,
                                                    int* __restrict__ rowlist) {
  __shared__ int h[NT];
  int tid = threadIdx.x;
  if (tid < NT) h[tid] = 0;
  __syncthreads();
  int row = blockIdx.x * 256 + tid;
  int t = tidx[row];
  int r = atomicAdd(&h[t], 1);
  rowlist[blkbase[blockIdx.x * NT + t] + r] = row;
}

// ---------------- gather: xsrt[p] = bf16(x[rowlist[p]]) (linear A for GEMM) ----------------
__global__ __launch_bounds__(512) void trix_gather(const float* __restrict__ x,
                                                   const int* __restrict__ rowlist,
                                                   ushort_t* __restrict__ xsrt) {
  int tid = threadIdx.x;
  int lane = tid & 63, wv = tid >> 6;
  int p = blockIdx.x * 8 + wv;
  int row = rowlist[p];
  const float* src = x + (size_t)row * ND + lane * 16;
  float4 v0 = *(const float4*)(src);
  float4 v1 = *(const float4*)(src + 4);
  float4 v2 = *(const float4*)(src + 8);
  float4 v3 = *(const float4*)(src + 12);
  ushort_t* dst = xsrt + (size_t)p * ND + lane * 16;
  *(uint4*)(dst) = make_uint4(pk2(v0.x, v0.y), pk2(v0.z, v0.w), pk2(v1.x, v1.y), pk2(v1.z, v1.w));
  *(uint4*)(dst + 8) = make_uint4(pk2(v2.x, v2.y), pk2(v2.z, v2.w), pk2(v3.x, v3.y), pk2(v3.z, v3.w));
}

// ---------------- m97-structure GEMM: 128x128 tile, BK=64, single-buffer LDS,
// sorted linear A, conflict-free chunk-XOR LDS (r5-verified pattern), 3 blocks/CU TLP.
__global__ __launch_bounds__(256, 3) void trix_gemm4(
    const ushort_t* __restrict__ xsrt, const ushort_t* __restrict__ wbf,
    const float* __restrict__ bias, const int* __restrict__ meta,
    const int* __restrict__ rowlist, float* __restrict__ out) {
  __shared__ __align__(16) ushort_t A_lds[128 * 64];  // 16 KB: 128 rows x 64 k
  __shared__ __align__(16) ushort_t B_lds[128 * 64];  // 16 KB
  __shared__ int rl[128];
  int bid = blockIdx.x;
  int w = (bid & 7) * 272 + (bid >> 3);  // bijective XCD chunk swizzle: 2176 = 8*272
  int nb = w & 7, rb = w >> 3;           // same rb, all nb consecutive on one XCD
  if (rb >= meta[66]) return;
  int t = 0;
  while (t < NT - 1 && rb >= meta[51 + t]) t++;
  int row0 = meta[16 + t] + (rb - meta[50 + t]) * 128;
  int cnt = meta[17 + t] - row0;
  if (cnt > 128) cnt = 128;
  int tid = threadIdx.x;
  if (tid < 128) rl[tid] = rowlist[(tid < cnt) ? (row0 + tid) : row0];

  int lane = tid & 63, wv = tid >> 6;
  // staging: wave wv covers rows [wv*32, wv*32+32) in 4 copies of 8 rows.
  // LDS[row][slot] holds global 16B-chunk (slot ^ (row&7)); dest linear (m104 rule).
  int srow = lane >> 3;                       // row%8 within copy
  int schunk = ((lane & 7) ^ srow) * 8;       // pre-swizzled source chunk (ushorts)
  const ushort_t* aSrc = xsrt + (size_t)(row0 + wv * 32 + srow) * ND + schunk;
  const ushort_t* bSrc =
      wbf + ((size_t)t << 20) + (size_t)(nb * 128 + wv * 32 + srow) * ND + schunk;
  ushort_t* aDst = A_lds + wv * 32 * 64 + lane * 8;
  ushort_t* bDst = B_lds + wv * 32 * 64 + lane * 8;

  int wr = wv >> 1, wc = wv & 1;  // 2M x 2N waves; per-wave 64x64 output
  int rsel = lane & 15, ksl = lane >> 4, rx = rsel & 7;
  int sl0 = (ksl ^ rx) * 8;        // k-half 0: global chunk ksl
  int sl1 = ((4 + ksl) ^ rx) * 8;  // k-half 1: global chunk 4+ksl
  int aoff = (wr * 64 + rsel) * 64;
  int boff = (wc * 64 + rsel) * 64;

  f32x4 acc[4][4] = {};

#pragma unroll 1
  for (int k0 = 0; k0 < ND; k0 += 64) {
#pragma unroll
    for (int j = 0; j < 4; j++) {
      async_copy16(aSrc + k0 + j * 8 * ND, aDst + j * 512);
      async_copy16(bSrc + k0 + j * 8 * ND, bDst + j * 512);
    }
    __syncthreads();
    short8 af[4][2], bf2[2][2];
#pragma unroll
    for (int m = 0; m < 4; m++) {
      af[m][0] = *(const short8*)(A_lds + aoff + m * 1024 + sl0);
      af[m][1] = *(const short8*)(A_lds + aoff + m * 1024 + sl1);
    }
#pragma unroll
    for (int nh = 0; nh < 2; nh++) {
#pragma unroll
      for (int j = 0; j < 2; j++) {
        int n = nh * 2 + j;
        bf2[j][0] = *(const short8*)(B_lds + boff + n * 1024 + sl0);
        bf2[j][1] = *(const short8*)(B_lds + boff + n * 1024 + sl1);
      }
#pragma unroll
      for (int m = 0; m < 4; m++)
#pragma unroll
        for (int j = 0; j < 2; j++) {
          acc[m][nh * 2 + j] = __builtin_amdgcn_mfma_f32_16x16x32_bf16(
              af[m][0], bf2[j][0], acc[m][nh * 2 + j], 0, 0, 0);
          acc[m][nh * 2 + j] = __builtin_amdgcn_mfma_f32_16x16x32_bf16(
              af[m][1], bf2[j][1], acc[m][nh * 2 + j], 0, 0, 0);
        }
    }
    __syncthreads();
  }

  // epilogue: C/D layout col=lane&15, row=(lane>>4)*4+reg
  float bv[4];
  int bcol[4];
#pragma unroll
  for (int n = 0; n < 4; ++n) {
    bcol[n] = nb * 128 + wc * 64 + n * 16 + rsel;
    bv[n] = (bcol[n] < NC) ? bias[t * NC + bcol[n]] : 0.0f;
  }
#pragma unroll
  for (int m = 0; m < 4; ++m) {
#pragma unroll
    for (int r = 0; r < 4; ++r) {
      int lr = wr * 64 + m * 16 + ksl * 4 + r;
      if (lr < cnt) {
        size_t ob = (size_t)rl[lr] * NC;
#pragma unroll
        for (int n = 0; n < 4; ++n)
          if (bcol[n] < NC) out[ob + bcol[n]] = acc[m][n][r] + bv[n];
      }
    }
  }
}

// ---------------- fallback GEMM (f32 inputs, in-loop repack), cb128 meta ----------------
__global__ __launch_bounds__(256) void trix_gemm_fb(
    const float* __restrict__ x, const float* __restrict__ W,
    const float* __restrict__ bias, const int* __restrict__ meta,
    const int* __restrict__ rowlist, float* __restrict__ out) {
  __shared__ __align__(16) unsigned char aT[128 * 64];
  __shared__ __align__(16) unsigned char bT[128 * 64];
  __shared__ int rl[128];
  int nb = blockIdx.x, rb = blockIdx.y;
  if (rb >= meta[66]) return;
  int t = 0;
  while (t < NT - 1 && rb >= meta[51 + t]) t++;
  int row0 = meta[16 + t] + (rb - meta[50 + t]) * 128;
  int cnt = meta[17 + t] - row0;
  if (cnt > 128) cnt = 128;
  int tid = threadIdx.x;
  if (tid < 128) rl[tid] = rowlist[(tid < cnt) ? (row0 + tid) : row0];
  __syncthreads();
  int half = tid & 1, rloc = tid >> 1;
  const float* xp = x + (size_t)rl[rloc] * ND + half * 16;
  int wn = nb * 128 + rloc;
  if (wn > NC - 1) wn = NC - 1;
  const float* wp = W + ((size_t)t * NC + wn) * ND + half * 16;
  int sw = swz(rloc);
  unsigned char* aw0 = aT + rloc * 64 + (((half * 2 + 0) ^ sw) << 4);
  unsigned char* aw1 = aT + rloc * 64 + (((half * 2 + 1) ^ sw) << 4);
  unsigned char* bw0 = bT + rloc * 64 + (((half * 2 + 0) ^ sw) << 4);
  unsigned char* bw1 = bT + rloc * 64 + (((half * 2 + 1) ^ sw) << 4);
  int lane = tid & 63, wv = tid >> 6;
  int wr = wv >> 1, wc = wv & 1;
  int rsel = lane & 15, slot = lane >> 4;
  f32x4 acc[4][4] = {};
  for (int k0 = 0; k0 < ND; k0 += 32) {
    const float* xk = xp + k0;
    const float* wk = wp + k0;
    float4 a0 = *(const float4*)(xk);
    float4 a1 = *(const float4*)(xk + 4);
    float4 a2 = *(const float4*)(xk + 8);
    float4 a3 = *(const float4*)(xk + 12);
    float4 b0 = *(const float4*)(wk);
    float4 b1 = *(const float4*)(wk + 4);
    float4 b2 = *(const float4*)(wk + 8);
    float4 b3 = *(const float4*)(wk + 12);
    *(uint4*)aw0 = make_uint4(pk2(a0.x, a0.y), pk2(a0.z, a0.w), pk2(a1.x, a1.y), pk2(a1.z, a1.w));
    *(uint4*)aw1 = make_uint4(pk2(a2.x, a2.y), pk2(a2.z, a2.w), pk2(a3.x, a3.y), pk2(a3.z, a3.w));
    *(uint4*)bw0 = make_uint4(pk2(b0.x, b0.y), pk2(b0.z, b0.w), pk2(b1.x, b1.y), pk2(b1.z, b1.w));
    *(uint4*)bw1 = make_uint4(pk2(b2.x, b2.y), pk2(b2.z, b2.w), pk2(b3.x, b3.y), pk2(b3.z, b3.w));
    __syncthreads();
    short8 af2[4], bfr[4];
#pragma unroll
    for (int i = 0; i < 4; i++) {
      int arr = wr * 64 + i * 16 + rsel;
      af2[i] = *(const short8*)(aT + arr * 64 + ((slot ^ swz(arr)) << 4));
      int brr = wc * 64 + i * 16 + rsel;
      bfr[i] = *(const short8*)(bT + brr * 64 + ((slot ^ swz(brr)) << 4));
    }
#pragma unroll
    for (int mi = 0; mi < 4; mi++)
#pragma unroll
      for (int ni = 0; ni < 4; ni++)
        acc[mi][ni] = __builtin_amdgcn_mfma_f32_16x16x32_bf16(af2[mi], bfr[ni], acc[mi][ni], 0, 0, 0);
    __syncthreads();
  }
#pragma unroll
  for (int mi = 0; mi < 4; mi++) {
#pragma unroll
    for (int r = 0; r < 4; r++) {
      int rloc2 = wr * 64 + mi * 16 + slot * 4 + r;
      if (rloc2 < cnt) {
        size_t obase = (size_t)rl[rloc2] * NC;
#pragma unroll
        for (int ni = 0; ni < 4; ni++) {
          int col = nb * 128 + wc * 64 + ni * 16 + rsel;
          if (col < NC) out[obase + col] = acc[mi][ni][r] + bias[t * NC + col];
        }
      }
    }
  }
}

extern "C" void kernel_launch(void* const* d_in, const int* in_sizes, int n_in,
                              void* d_out, int out_size, void* d_ws, size_t ws_size,
                              hipStream_t stream) {
  const float* x = (const float*)d_in[0];
  const float* sigs = (const float*)d_in[1];
  const float* W = (const float*)d_in[2];
  const float* bias = (const float*)d_in[3];
  float* out = (float*)d_out;

  const size_t XSRT_B = (size_t)(NBROWS + 256) * ND * 2;  // sorted bf16 A (+pad rows)
  const size_t WBF_B = (size_t)NT * 1024 * ND * 2;        // 33,554,432
  bool fast = ws_size >= XSRT_B + WBF_B + (1 << 20);

  char* wsb = (char*)d_ws;
  ushort_t* xsrt = nullptr;
  ushort_t* wbf = nullptr;
  int* tidx;
  if (fast) {
    xsrt = (ushort_t*)wsb;
    wbf = (ushort_t*)(wsb + XSRT_B);
    tidx = (int*)(wsb + XSRT_B + WBF_B);
  } else {
    tidx = (int*)wsb;
  }
  int* rowlist = tidx + NBROWS;
  int* meta = rowlist + NBROWS;
  int* blkhist = meta + 80;
  int* blkbase = blkhist + NHB * NT;

  fused_pre<<<8192, 512, 0, stream>>>(x, sigs, tidx, out + (size_t)NBROWS * NC, W, wbf);
  trix_hist<<<NHB, 256, 0, stream>>>(tidx, blkhist);
  trix_prefix<<<1, 256, 0, stream>>>(blkhist, blkbase, meta);
  trix_scatter<<<NHB, 256, 0, stream>>>(tidx, blkbase, rowlist);
  if (fast) {
    trix_gather<<<NBROWS / 8, 512, 0, stream>>>(x, rowlist, xsrt);
    trix_gemm4<<<8 * MAX_RB128, 256, 0, stream>>>(xsrt, wbf, bias, meta, rowlist, out);
  } else {
    trix_gemm_fb<<<dim3(8, MAX_RB128), 256, 0, stream>>>(x, W, bias, meta, rowlist, out);
  }
}

// Round 8
// 204.213 us; speedup vs baseline: 1.2329x; 1.0713x over previous
//
#include <hip/hip_runtime.h>

#define NBROWS 32768
#define ND 1024
#define NT 16
#define NC 1000
#define NHB 128
#define MAX_RB128 272  // worst-case 128-row blocks: 32768/128 + 16

typedef short short8 __attribute__((ext_vector_type(8)));
typedef float f32x4 __attribute__((ext_vector_type(4)));
typedef unsigned short ushort_t;

typedef __attribute__((address_space(1))) const unsigned int* gas_t;
typedef __attribute__((address_space(3))) unsigned int* las_t;

__device__ __forceinline__ void async_copy16(const void* g, void* l) {
  __builtin_amdgcn_global_load_lds((gas_t)g, (las_t)l, 16, 0, 0);
}

__device__ __forceinline__ unsigned f2bf(float f) {
  unsigned u = __float_as_uint(f);
  u += 0x7FFFu + ((u >> 16) & 1u);  // round-nearest-even
  return u >> 16;
}
__device__ __forceinline__ unsigned pk2(float a, float b) {
  return f2bf(a) | (f2bf(b) << 16);
}
__device__ __forceinline__ int swz(int row) { return (row & 3) ^ ((row >> 2) & 3); }

// ---------------- fused scores + x->bf16 + W-conversion ----------------
__global__ __launch_bounds__(512) void fused_pre(
    const float* __restrict__ x, const float* __restrict__ sigs_raw,
    int* __restrict__ tidx, float* __restrict__ out_idx,
    const float* __restrict__ W, ushort_t* __restrict__ wbf,
    ushort_t* __restrict__ xbf) {
  __shared__ signed char s_lds[NT * ND];
  int tid = threadIdx.x;
  int bid = blockIdx.x;
  if (bid >= 4096) {
    if (!wbf) return;
    size_t e = (((size_t)(bid - 4096)) * 512 + tid) * 8;
    int t = (int)(e >> 20);
    int rem = (int)(e & 1048575);
    int col = rem >> 10, k = rem & 1023;
    uint4 o;
    if (col < NC) {
      const float* src = W + ((size_t)t * NC + col) * ND + k;
      float4 a = *(const float4*)src;
      float4 b = *(const float4*)(src + 4);
      o = make_uint4(pk2(a.x, a.y), pk2(a.z, a.w), pk2(b.x, b.y), pk2(b.z, b.w));
    } else {
      o = make_uint4(0, 0, 0, 0);
    }
    *(uint4*)(wbf + e) = o;
    return;
  }
  for (int i = tid; i < NT * ND; i += 512) {
    float s = sigs_raw[i];
    s_lds[i] = (s > 0.3f) ? 1 : ((s < -0.3f) ? -1 : 0);
  }
  __syncthreads();
  int lane = tid & 63;
  int row = bid * 8 + (tid >> 6);
  const float* xr = x + (size_t)row * ND + lane * 16;
  float4 v0 = *(const float4*)(xr);
  float4 v1 = *(const float4*)(xr + 4);
  float4 v2 = *(const float4*)(xr + 8);
  float4 v3 = *(const float4*)(xr + 12);
  float xv[16] = {v0.x, v0.y, v0.z, v0.w, v1.x, v1.y, v1.z, v1.w,
                  v2.x, v2.y, v2.z, v2.w, v3.x, v3.y, v3.z, v3.w};
  if (xbf) {
    ushort_t* xo = xbf + (size_t)row * ND + lane * 16;
    *(uint4*)(xo) = make_uint4(pk2(v0.x, v0.y), pk2(v0.z, v0.w), pk2(v1.x, v1.y), pk2(v1.z, v1.w));
    *(uint4*)(xo + 8) = make_uint4(pk2(v2.x, v2.y), pk2(v2.z, v2.w), pk2(v3.x, v3.y), pk2(v3.z, v3.w));
  }
  float best = 0.0f;
  int bt = 0;
#pragma unroll
  for (int t = 0; t < NT; t++) {
    int4 sc = *(const int4*)(s_lds + t * ND + lane * 16);
    int wa[4] = {sc.x, sc.y, sc.z, sc.w};
    float p = 0.0f;
#pragma unroll
    for (int wi = 0; wi < 4; wi++)
#pragma unroll
      for (int bi = 0; bi < 4; bi++)
        p = fmaf((float)(signed char)(wa[wi] >> (8 * bi)), xv[wi * 4 + bi], p);
#pragma unroll
    for (int o = 32; o > 0; o >>= 1) p += __shfl_xor(p, o);
    if (t == 0 || p > best) { best = p; bt = t; }  // strict >: first index on tie (jnp.argmax)
  }
  if (lane == 0) {
    tidx[row] = bt;
    out_idx[row] = (float)bt;
  }
}

// ---------------- histogram / prefix / scatter (no global atomics) ----------------
__global__ __launch_bounds__(256) void trix_hist(const int* __restrict__ tidx,
                                                 int* __restrict__ blkhist) {
  __shared__ int h[NT];
  int tid = threadIdx.x;
  if (tid < NT) h[tid] = 0;
  __syncthreads();
  int t = tidx[blockIdx.x * 256 + tid];
  atomicAdd(&h[t], 1);
  __syncthreads();
  if (tid < NT) blkhist[blockIdx.x * NT + tid] = h[tid];
}

// meta: [0..15] counts, [16..32] row offsets, [50..66] cb128 (66=total)
__global__ __launch_bounds__(256) void trix_prefix(const int* __restrict__ blkhist,
                                                   int* __restrict__ blkbase,
                                                   int* __restrict__ meta) {
  __shared__ int part[NT][16];
  int tid = threadIdx.x;
  int t = tid >> 4, g = tid & 15;
  int s = 0;
  for (int b = g; b < NHB; b += 16) s += blkhist[b * NT + t];
  part[t][g] = s;
  __syncthreads();
  if (tid == 0) {
    int off = 0, cb2 = 0;
    for (int tt = 0; tt < NT; tt++) {
      int c = 0;
#pragma unroll
      for (int gg = 0; gg < 16; gg++) c += part[tt][gg];
      meta[tt] = c;
      meta[16 + tt] = off;
      meta[50 + tt] = cb2;
      off += c;
      cb2 += (c + 127) >> 7;
    }
    meta[32] = off;
    meta[66] = cb2;
  }
  __syncthreads();
  if (tid < NT) {
    int run = meta[16 + tid];
    for (int b = 0; b < NHB; b++) {
      blkbase[b * NT + tid] = run;
      run += blkhist[b * NT + tid];
    }
  }
}

__global__ __launch_bounds__(256) void trix_scatter(const int* __restrict__ tidx,
                                                    const int* __restrict__ blkbase,
                                                    int* __restrict__ rowlist) {
  __shared__ int h[NT];
  int tid = threadIdx.x;
  if (tid < NT) h[tid] = 0;
  __syncthreads();
  int row = blockIdx.x * 256 + tid;
  int t = tidx[row];
  int r = atomicAdd(&h[t], 1);
  rowlist[blkbase[blockIdx.x * NT + t] + r] = row;
}

// ---------------- GEMM: 128x128 tile, BK=64, DOUBLE-buffered LDS, direct
// per-lane gathered A staging from xbf (rl rows), conflict-free chunk-XOR LDS.
__global__ __launch_bounds__(256, 2) void trix_gemm5(
    const ushort_t* __restrict__ xbf, const ushort_t* __restrict__ wbf,
    const float* __restrict__ bias, const int* __restrict__ meta,
    const int* __restrict__ rowlist, float* __restrict__ out) {
  __shared__ __align__(16) ushort_t A_lds[2][128 * 64];  // 2 x 16 KB
  __shared__ __align__(16) ushort_t B_lds[2][128 * 64];  // 2 x 16 KB
  __shared__ int rl[128];
  int bid = blockIdx.x;
  int w = (bid & 7) * 272 + (bid >> 3);  // bijective XCD chunk swizzle: 2176 = 8*272
  int nb = w & 7, rb = w >> 3;
  if (rb >= meta[66]) return;
  int t = 0;
  while (t < NT - 1 && rb >= meta[51 + t]) t++;
  int row0 = meta[16 + t] + (rb - meta[50 + t]) * 128;
  int cnt = meta[17 + t] - row0;
  if (cnt > 128) cnt = 128;
  int tid = threadIdx.x;
  if (tid < 128) rl[tid] = rowlist[(tid < cnt) ? (row0 + tid) : row0];
  __syncthreads();

  int lane = tid & 63, wv = tid >> 6;
  // staging: wave wv covers rows [wv*32, wv*32+32) in 4 copies of 8 rows.
  // LDS[row][slot] holds global 16B-chunk (slot ^ (row&7)); dest linear (m104 rule).
  int srow = lane >> 3;                  // row%8 within copy
  int schunk = ((lane & 7) ^ srow) * 8;  // pre-swizzled source chunk (ushorts)
  const ushort_t* aS[4];
  const ushort_t* bS[4];
#pragma unroll
  for (int j = 0; j < 4; j++) {
    aS[j] = xbf + (size_t)rl[wv * 32 + j * 8 + srow] * ND + schunk;
    bS[j] = wbf + ((size_t)t << 20) + (size_t)(nb * 128 + wv * 32 + j * 8 + srow) * ND + schunk;
  }
  int ldst = wv * 2048 + lane * 8;  // wv*32*64 + lane*8 (ushorts), +j*512 per copy

  int wr = wv >> 1, wc = wv & 1;  // 2M x 2N waves; per-wave 64x64 output
  int rsel = lane & 15, ksl = lane >> 4, rx = rsel & 7;
  int sl0 = (ksl ^ rx) * 8;        // k-half 0: global chunk ksl
  int sl1 = ((4 + ksl) ^ rx) * 8;  // k-half 1: global chunk 4+ksl
  int aoff = (wr * 64 + rsel) * 64;
  int boff = (wc * 64 + rsel) * 64;

  f32x4 acc[4][4] = {};

#define STAGE(DB, KTL)                                       \
  _Pragma("unroll") for (int j = 0; j < 4; j++) {            \
    async_copy16(aS[j] + (KTL) * 64, &A_lds[DB][ldst + j * 512]); \
    async_copy16(bS[j] + (KTL) * 64, &B_lds[DB][ldst + j * 512]); \
  }

#define COMPUTE(DB)                                                          \
  {                                                                          \
    short8 af[4][2], bf2[2][2];                                              \
    _Pragma("unroll") for (int m = 0; m < 4; m++) {                          \
      af[m][0] = *(const short8*)(&A_lds[DB][aoff + m * 1024 + sl0]);        \
      af[m][1] = *(const short8*)(&A_lds[DB][aoff + m * 1024 + sl1]);        \
    }                                                                        \
    _Pragma("unroll") for (int nh = 0; nh < 2; nh++) {                       \
      _Pragma("unroll") for (int j = 0; j < 2; j++) {                        \
        int n = nh * 2 + j;                                                  \
        bf2[j][0] = *(const short8*)(&B_lds[DB][boff + n * 1024 + sl0]);     \
        bf2[j][1] = *(const short8*)(&B_lds[DB][boff + n * 1024 + sl1]);     \
      }                                                                      \
      _Pragma("unroll") for (int m = 0; m < 4; m++)                          \
          _Pragma("unroll") for (int j = 0; j < 2; j++) {                    \
        acc[m][nh * 2 + j] = __builtin_amdgcn_mfma_f32_16x16x32_bf16(        \
            af[m][0], bf2[j][0], acc[m][nh * 2 + j], 0, 0, 0);               \
        acc[m][nh * 2 + j] = __builtin_amdgcn_mfma_f32_16x16x32_bf16(        \
            af[m][1], bf2[j][1], acc[m][nh * 2 + j], 0, 0, 0);               \
      }                                                                      \
    }                                                                        \
  }

  // prologue: stage k-tile 0 into buf 0 (syncthreads drains vmcnt)
  STAGE(0, 0);
  __syncthreads();

#pragma unroll 1
  for (int kt = 0; kt < 8; ++kt) {
    STAGE(1, 2 * kt + 1);  // prefetch odd tile while computing even
    COMPUTE(0);
    __syncthreads();  // drains prefetch + protects buf0 reuse
    if (kt < 7) STAGE(0, 2 * kt + 2);  // prefetch next even while computing odd
    COMPUTE(1);
    __syncthreads();
  }

  // epilogue: C/D layout col=lane&15, row=(lane>>4)*4+reg
  float bv[4];
  int bcol[4];
#pragma unroll
  for (int n = 0; n < 4; ++n) {
    bcol[n] = nb * 128 + wc * 64 + n * 16 + rsel;
    bv[n] = (bcol[n] < NC) ? bias[t * NC + bcol[n]] : 0.0f;
  }
#pragma unroll
  for (int m = 0; m < 4; ++m) {
#pragma unroll
    for (int r = 0; r < 4; ++r) {
      int lr = wr * 64 + m * 16 + ksl * 4 + r;
      if (lr < cnt) {
        size_t ob = (size_t)rl[lr] * NC;
#pragma unroll
        for (int n = 0; n < 4; ++n)
          if (bcol[n] < NC) out[ob + bcol[n]] = acc[m][n][r] + bv[n];
      }
    }
  }
#undef STAGE
#undef COMPUTE
}

// ---------------- fallback GEMM (f32 inputs, in-loop repack), cb128 meta ----------------
__global__ __launch_bounds__(256) void trix_gemm_fb(
    const float* __restrict__ x, const float* __restrict__ W,
    const float* __restrict__ bias, const int* __restrict__ meta,
    const int* __restrict__ rowlist, float* __restrict__ out) {
  __shared__ __align__(16) unsigned char aT[128 * 64];
  __shared__ __align__(16) unsigned char bT[128 * 64];
  __shared__ int rl[128];
  int nb = blockIdx.x, rb = blockIdx.y;
  if (rb >= meta[66]) return;
  int t = 0;
  while (t < NT - 1 && rb >= meta[51 + t]) t++;
  int row0 = meta[16 + t] + (rb - meta[50 + t]) * 128;
  int cnt = meta[17 + t] - row0;
  if (cnt > 128) cnt = 128;
  int tid = threadIdx.x;
  if (tid < 128) rl[tid] = rowlist[(tid < cnt) ? (row0 + tid) : row0];
  __syncthreads();
  int half = tid & 1, rloc = tid >> 1;
  const float* xp = x + (size_t)rl[rloc] * ND + half * 16;
  int wn = nb * 128 + rloc;
  if (wn > NC - 1) wn = NC - 1;
  const float* wp = W + ((size_t)t * NC + wn) * ND + half * 16;
  int sw = swz(rloc);
  unsigned char* aw0 = aT + rloc * 64 + (((half * 2 + 0) ^ sw) << 4);
  unsigned char* aw1 = aT + rloc * 64 + (((half * 2 + 1) ^ sw) << 4);
  unsigned char* bw0 = bT + rloc * 64 + (((half * 2 + 0) ^ sw) << 4);
  unsigned char* bw1 = bT + rloc * 64 + (((half * 2 + 1) ^ sw) << 4);
  int lane = tid & 63, wv = tid >> 6;
  int wr = wv >> 1, wc = wv & 1;
  int rsel = lane & 15, slot = lane >> 4;
  f32x4 acc[4][4] = {};
  for (int k0 = 0; k0 < ND; k0 += 32) {
    const float* xk = xp + k0;
    const float* wk = wp + k0;
    float4 a0 = *(const float4*)(xk);
    float4 a1 = *(const float4*)(xk + 4);
    float4 a2 = *(const float4*)(xk + 8);
    float4 a3 = *(const float4*)(xk + 12);
    float4 b0 = *(const float4*)(wk);
    float4 b1 = *(const float4*)(wk + 4);
    float4 b2 = *(const float4*)(wk + 8);
    float4 b3 = *(const float4*)(wk + 12);
    *(uint4*)aw0 = make_uint4(pk2(a0.x, a0.y), pk2(a0.z, a0.w), pk2(a1.x, a1.y), pk2(a1.z, a1.w));
    *(uint4*)aw1 = make_uint4(pk2(a2.x, a2.y), pk2(a2.z, a2.w), pk2(a3.x, a3.y), pk2(a3.z, a3.w));
    *(uint4*)bw0 = make_uint4(pk2(b0.x, b0.y), pk2(b0.z, b0.w), pk2(b1.x, b1.y), pk2(b1.z, b1.w));
    *(uint4*)bw1 = make_uint4(pk2(b2.x, b2.y), pk2(b2.z, b2.w), pk2(b3.x, b3.y), pk2(b3.z, b3.w));
    __syncthreads();
    short8 af2[4], bfr[4];
#pragma unroll
    for (int i = 0; i < 4; i++) {
      int arr = wr * 64 + i * 16 + rsel;
      af2[i] = *(const short8*)(aT + arr * 64 + ((slot ^ swz(arr)) << 4));
      int brr = wc * 64 + i * 16 + rsel;
      bfr[i] = *(const short8*)(bT + brr * 64 + ((slot ^ swz(brr)) << 4));
    }
#pragma unroll
    for (int mi = 0; mi < 4; mi++)
#pragma unroll
      for (int ni = 0; ni < 4; ni++)
        acc[mi][ni] = __builtin_amdgcn_mfma_f32_16x16x32_bf16(af2[mi], bfr[ni], acc[mi][ni], 0, 0, 0);
    __syncthreads();
  }
#pragma unroll
  for (int mi = 0; mi < 4; mi++) {
#pragma unroll
    for (int r = 0; r < 4; r++) {
      int rloc2 = wr * 64 + mi * 16 + slot * 4 + r;
      if (rloc2 < cnt) {
        size_t obase = (size_t)rl[rloc2] * NC;
#pragma unroll
        for (int ni = 0; ni < 4; ni++) {
          int col = nb * 128 + wc * 64 + ni * 16 + rsel;
          if (col < NC) out[obase + col] = acc[mi][ni][r] + bias[t * NC + col];
        }
      }
    }
  }
}

extern "C" void kernel_launch(void* const* d_in, const int* in_sizes, int n_in,
                              void* d_out, int out_size, void* d_ws, size_t ws_size,
                              hipStream_t stream) {
  const float* x = (const float*)d_in[0];
  const float* sigs = (const float*)d_in[1];
  const float* W = (const float*)d_in[2];
  const float* bias = (const float*)d_in[3];
  float* out = (float*)d_out;

  const size_t XBF_B = (size_t)NBROWS * ND * 2;    // 67,108,864
  const size_t WBF_B = (size_t)NT * 1024 * ND * 2; // 33,554,432
  bool fast = ws_size >= XBF_B + WBF_B + (1 << 20);

  char* wsb = (char*)d_ws;
  ushort_t* xbf = nullptr;
  ushort_t* wbf = nullptr;
  int* tidx;
  if (fast) {
    xbf = (ushort_t*)wsb;
    wbf = (ushort_t*)(wsb + XBF_B);
    tidx = (int*)(wsb + XBF_B + WBF_B);
  } else {
    tidx = (int*)wsb;
  }
  int* rowlist = tidx + NBROWS;
  int* meta = rowlist + NBROWS;
  int* blkhist = meta + 80;
  int* blkbase = blkhist + NHB * NT;

  fused_pre<<<8192, 512, 0, stream>>>(x, sigs, tidx, out + (size_t)NBROWS * NC, W, wbf, xbf);
  trix_hist<<<NHB, 256, 0, stream>>>(tidx, blkhist);
  trix_prefix<<<1, 256, 0, stream>>>(blkhist, blkbase, meta);
  trix_scatter<<<NHB, 256, 0, stream>>>(tidx, blkbase, rowlist);
  if (fast) {
    trix_gemm5<<<8 * MAX_RB128, 256, 0, stream>>>(xbf, wbf, bias, meta, rowlist, out);
  } else {
    trix_gemm_fb<<<dim3(8, MAX_RB128), 256, 0, stream>>>(x, W, bias, meta, rowlist, out);
  }
}

// Round 9
// 179.678 us; speedup vs baseline: 1.4013x; 1.1366x over previous
//
#include <hip/hip_runtime.h>

#define NBROWS 32768
#define ND 1024
#define NT 16
#define NC 1000
#define NHB 128
#define MAX_RB128 272  // worst-case 128-row blocks: 32768/128 + 16

typedef short short8 __attribute__((ext_vector_type(8)));
typedef float f32x4 __attribute__((ext_vector_type(4)));
typedef unsigned short ushort_t;

typedef __attribute__((address_space(1))) const unsigned int* gas_t;
typedef __attribute__((address_space(3))) unsigned int* las_t;

__device__ __forceinline__ void async_copy16(const void* g, void* l) {
  __builtin_amdgcn_global_load_lds((gas_t)g, (las_t)l, 16, 0, 0);
}

__device__ __forceinline__ unsigned f2bf(float f) {
  unsigned u = __float_as_uint(f);
  u += 0x7FFFu + ((u >> 16) & 1u);  // round-nearest-even
  return u >> 16;
}
__device__ __forceinline__ unsigned pk2(float a, float b) {
  return f2bf(a) | (f2bf(b) << 16);
}
__device__ __forceinline__ int swz(int row) { return (row & 3) ^ ((row >> 2) & 3); }

// ---------------- fused scores + x->bf16 + W-conversion ----------------
__global__ __launch_bounds__(512) void fused_pre(
    const float* __restrict__ x, const float* __restrict__ sigs_raw,
    int* __restrict__ tidx, float* __restrict__ out_idx,
    const float* __restrict__ W, ushort_t* __restrict__ wbf,
    ushort_t* __restrict__ xbf) {
  __shared__ signed char s_lds[NT * ND];
  int tid = threadIdx.x;
  int bid = blockIdx.x;
  if (bid >= 4096) {
    if (!wbf) return;
    size_t e = (((size_t)(bid - 4096)) * 512 + tid) * 8;
    int t = (int)(e >> 20);
    int rem = (int)(e & 1048575);
    int col = rem >> 10, k = rem & 1023;
    uint4 o;
    if (col < NC) {
      const float* src = W + ((size_t)t * NC + col) * ND + k;
      float4 a = *(const float4*)src;
      float4 b = *(const float4*)(src + 4);
      o = make_uint4(pk2(a.x, a.y), pk2(a.z, a.w), pk2(b.x, b.y), pk2(b.z, b.w));
    } else {
      o = make_uint4(0, 0, 0, 0);
    }
    *(uint4*)(wbf + e) = o;
    return;
  }
  for (int i = tid; i < NT * ND; i += 512) {
    float s = sigs_raw[i];
    s_lds[i] = (s > 0.3f) ? 1 : ((s < -0.3f) ? -1 : 0);
  }
  __syncthreads();
  int lane = tid & 63;
  int row = bid * 8 + (tid >> 6);
  const float* xr = x + (size_t)row * ND + lane * 16;
  float4 v0 = *(const float4*)(xr);
  float4 v1 = *(const float4*)(xr + 4);
  float4 v2 = *(const float4*)(xr + 8);
  float4 v3 = *(const float4*)(xr + 12);
  float xv[16] = {v0.x, v0.y, v0.z, v0.w, v1.x, v1.y, v1.z, v1.w,
                  v2.x, v2.y, v2.z, v2.w, v3.x, v3.y, v3.z, v3.w};
  if (xbf) {
    ushort_t* xo = xbf + (size_t)row * ND + lane * 16;
    *(uint4*)(xo) = make_uint4(pk2(v0.x, v0.y), pk2(v0.z, v0.w), pk2(v1.x, v1.y), pk2(v1.z, v1.w));
    *(uint4*)(xo + 8) = make_uint4(pk2(v2.x, v2.y), pk2(v2.z, v2.w), pk2(v3.x, v3.y), pk2(v3.z, v3.w));
  }
  float best = 0.0f;
  int bt = 0;
#pragma unroll
  for (int t = 0; t < NT; t++) {
    int4 sc = *(const int4*)(s_lds + t * ND + lane * 16);
    int wa[4] = {sc.x, sc.y, sc.z, sc.w};
    float p = 0.0f;
#pragma unroll
    for (int wi = 0; wi < 4; wi++)
#pragma unroll
      for (int bi = 0; bi < 4; bi++)
        p = fmaf((float)(signed char)(wa[wi] >> (8 * bi)), xv[wi * 4 + bi], p);
#pragma unroll
    for (int o = 32; o > 0; o >>= 1) p += __shfl_xor(p, o);
    if (t == 0 || p > best) { best = p; bt = t; }  // strict >: first index on tie (jnp.argmax)
  }
  if (lane == 0) {
    tidx[row] = bt;
    out_idx[row] = (float)bt;
  }
}

// ---------------- histogram / prefix / scatter (no global atomics) ----------------
__global__ __launch_bounds__(256) void trix_hist(const int* __restrict__ tidx,
                                                 int* __restrict__ blkhist) {
  __shared__ int h[NT];
  int tid = threadIdx.x;
  if (tid < NT) h[tid] = 0;
  __syncthreads();
  int t = tidx[blockIdx.x * 256 + tid];
  atomicAdd(&h[t], 1);
  __syncthreads();
  if (tid < NT) blkhist[blockIdx.x * NT + tid] = h[tid];
}

// meta: [0..15] counts, [16..32] row offsets, [50..66] cb128 (66=total)
__global__ __launch_bounds__(256) void trix_prefix(const int* __restrict__ blkhist,
                                                   int* __restrict__ blkbase,
                                                   int* __restrict__ meta) {
  __shared__ int part[NT][16];
  int tid = threadIdx.x;
  int t = tid >> 4, g = tid & 15;
  int s = 0;
  for (int b = g; b < NHB; b += 16) s += blkhist[b * NT + t];
  part[t][g] = s;
  __syncthreads();
  if (tid == 0) {
    int off = 0, cb2 = 0;
    for (int tt = 0; tt < NT; tt++) {
      int c = 0;
#pragma unroll
      for (int gg = 0; gg < 16; gg++) c += part[tt][gg];
      meta[tt] = c;
      meta[16 + tt] = off;
      meta[50 + tt] = cb2;
      off += c;
      cb2 += (c + 127) >> 7;
    }
    meta[32] = off;
    meta[66] = cb2;
  }
  __syncthreads();
  if (tid < NT) {
    int run = meta[16 + tid];
    for (int b = 0; b < NHB; b++) {
      blkbase[b * NT + tid] = run;
      run += blkhist[b * NT + tid];
    }
  }
}

__global__ __launch_bounds__(256) void trix_scatter(const int* __restrict__ tidx,
                                                    const int* __restrict__ blkbase,
                                                    int* __restrict__ rowlist) {
  __shared__ int h[NT];
  int tid = threadIdx.x;
  if (tid < NT) h[tid] = 0;
  __syncthreads();
  int row = blockIdx.x * 256 + tid;
  int t = tidx[row];
  int r = atomicAdd(&h[t], 1);
  rowlist[blkbase[blockIdx.x * NT + t] + r] = row;
}

// ---------------- GEMM: 128x128 tile, BK=64, SINGLE-buffer LDS (r7 structure),
// direct per-lane gathered A staging from xbf (rl rows), conflict-free chunk-XOR LDS.
__global__ __launch_bounds__(256, 3) void trix_gemm6(
    const ushort_t* __restrict__ xbf, const ushort_t* __restrict__ wbf,
    const float* __restrict__ bias, const int* __restrict__ meta,
    const int* __restrict__ rowlist, float* __restrict__ out) {
  __shared__ __align__(16) ushort_t A_lds[128 * 64];  // 16 KB: 128 rows x 64 k
  __shared__ __align__(16) ushort_t B_lds[128 * 64];  // 16 KB
  __shared__ int rl[128];
  int bid = blockIdx.x;
  int w = (bid & 7) * 272 + (bid >> 3);  // bijective XCD chunk swizzle: 2176 = 8*272
  int nb = w & 7, rb = w >> 3;           // each XCD owns 34 rb panels x all 8 nb
  if (rb >= meta[66]) return;
  int t = 0;
  while (t < NT - 1 && rb >= meta[51 + t]) t++;
  int row0 = meta[16 + t] + (rb - meta[50 + t]) * 128;
  int cnt = meta[17 + t] - row0;
  if (cnt > 128) cnt = 128;
  int tid = threadIdx.x;
  if (tid < 128) rl[tid] = rowlist[(tid < cnt) ? (row0 + tid) : row0];
  __syncthreads();

  int lane = tid & 63, wv = tid >> 6;
  // staging: wave wv covers rows [wv*32, wv*32+32) in 4 copies of 8 rows.
  // LDS[row][slot] holds global 16B-chunk (slot ^ (row&7)); dest linear (m104 rule).
  int srow = lane >> 3;                  // row%8 within copy
  int schunk = ((lane & 7) ^ srow) * 8;  // pre-swizzled source chunk (ushorts)
  const ushort_t* aS[4];
  const ushort_t* bS[4];
#pragma unroll
  for (int j = 0; j < 4; j++) {
    aS[j] = xbf + (size_t)rl[wv * 32 + j * 8 + srow] * ND + schunk;
    bS[j] = wbf + ((size_t)t << 20) + (size_t)(nb * 128 + wv * 32 + j * 8 + srow) * ND + schunk;
  }
  int ldst = wv * 2048 + lane * 8;  // wv*32*64 + lane*8 (ushorts), +j*512 per copy

  int wr = wv >> 1, wc = wv & 1;  // 2M x 2N waves; per-wave 64x64 output
  int rsel = lane & 15, ksl = lane >> 4, rx = rsel & 7;
  int sl0 = (ksl ^ rx) * 8;        // k-half 0: global chunk ksl
  int sl1 = ((4 + ksl) ^ rx) * 8;  // k-half 1: global chunk 4+ksl
  int aoff = (wr * 64 + rsel) * 64;
  int boff = (wc * 64 + rsel) * 64;

  f32x4 acc[4][4] = {};

#pragma unroll 1
  for (int k0 = 0; k0 < ND; k0 += 64) {
#pragma unroll
    for (int j = 0; j < 4; j++) {
      async_copy16(aS[j] + k0, &A_lds[ldst + j * 512]);
      async_copy16(bS[j] + k0, &B_lds[ldst + j * 512]);
    }
    __syncthreads();
    short8 af[4][2], bf2[2][2];
#pragma unroll
    for (int m = 0; m < 4; m++) {
      af[m][0] = *(const short8*)(&A_lds[aoff + m * 1024 + sl0]);
      af[m][1] = *(const short8*)(&A_lds[aoff + m * 1024 + sl1]);
    }
#pragma unroll
    for (int nh = 0; nh < 2; nh++) {
#pragma unroll
      for (int j = 0; j < 2; j++) {
        int n = nh * 2 + j;
        bf2[j][0] = *(const short8*)(&B_lds[boff + n * 1024 + sl0]);
        bf2[j][1] = *(const short8*)(&B_lds[boff + n * 1024 + sl1]);
      }
#pragma unroll
      for (int m = 0; m < 4; m++)
#pragma unroll
        for (int j = 0; j < 2; j++) {
          acc[m][nh * 2 + j] = __builtin_amdgcn_mfma_f32_16x16x32_bf16(
              af[m][0], bf2[j][0], acc[m][nh * 2 + j], 0, 0, 0);
          acc[m][nh * 2 + j] = __builtin_amdgcn_mfma_f32_16x16x32_bf16(
              af[m][1], bf2[j][1], acc[m][nh * 2 + j], 0, 0, 0);
        }
    }
    __syncthreads();
  }

  // epilogue: C/D layout col=lane&15, row=(lane>>4)*4+reg
  float bv[4];
  int bcol[4];
#pragma unroll
  for (int n = 0; n < 4; ++n) {
    bcol[n] = nb * 128 + wc * 64 + n * 16 + rsel;
    bv[n] = (bcol[n] < NC) ? bias[t * NC + bcol[n]] : 0.0f;
  }
#pragma unroll
  for (int m = 0; m < 4; ++m) {
#pragma unroll
    for (int r = 0; r < 4; ++r) {
      int lr = wr * 64 + m * 16 + ksl * 4 + r;
      if (lr < cnt) {
        size_t ob = (size_t)rl[lr] * NC;
#pragma unroll
        for (int n = 0; n < 4; ++n)
          if (bcol[n] < NC) out[ob + bcol[n]] = acc[m][n][r] + bv[n];
      }
    }
  }
}

// ---------------- fallback GEMM (f32 inputs, in-loop repack), cb128 meta ----------------
__global__ __launch_bounds__(256) void trix_gemm_fb(
    const float* __restrict__ x, const float* __restrict__ W,
    const float* __restrict__ bias, const int* __restrict__ meta,
    const int* __restrict__ rowlist, float* __restrict__ out) {
  __shared__ __align__(16) unsigned char aT[128 * 64];
  __shared__ __align__(16) unsigned char bT[128 * 64];
  __shared__ int rl[128];
  int nb = blockIdx.x, rb = blockIdx.y;
  if (rb >= meta[66]) return;
  int t = 0;
  while (t < NT - 1 && rb >= meta[51 + t]) t++;
  int row0 = meta[16 + t] + (rb - meta[50 + t]) * 128;
  int cnt = meta[17 + t] - row0;
  if (cnt > 128) cnt = 128;
  int tid = threadIdx.x;
  if (tid < 128) rl[tid] = rowlist[(tid < cnt) ? (row0 + tid) : row0];
  __syncthreads();
  int half = tid & 1, rloc = tid >> 1;
  const float* xp = x + (size_t)rl[rloc] * ND + half * 16;
  int wn = nb * 128 + rloc;
  if (wn > NC - 1) wn = NC - 1;
  const float* wp = W + ((size_t)t * NC + wn) * ND + half * 16;
  int sw = swz(rloc);
  unsigned char* aw0 = aT + rloc * 64 + (((half * 2 + 0) ^ sw) << 4);
  unsigned char* aw1 = aT + rloc * 64 + (((half * 2 + 1) ^ sw) << 4);
  unsigned char* bw0 = bT + rloc * 64 + (((half * 2 + 0) ^ sw) << 4);
  unsigned char* bw1 = bT + rloc * 64 + (((half * 2 + 1) ^ sw) << 4);
  int lane = tid & 63, wv = tid >> 6;
  int wr = wv >> 1, wc = wv & 1;
  int rsel = lane & 15, slot = lane >> 4;
  f32x4 acc[4][4] = {};
  for (int k0 = 0; k0 < ND; k0 += 32) {
    const float* xk = xp + k0;
    const float* wk = wp + k0;
    float4 a0 = *(const float4*)(xk);
    float4 a1 = *(const float4*)(xk + 4);
    float4 a2 = *(const float4*)(xk + 8);
    float4 a3 = *(const float4*)(xk + 12);
    float4 b0 = *(const float4*)(wk);
    float4 b1 = *(const float4*)(wk + 4);
    float4 b2 = *(const float4*)(wk + 8);
    float4 b3 = *(const float4*)(wk + 12);
    *(uint4*)aw0 = make_uint4(pk2(a0.x, a0.y), pk2(a0.z, a0.w), pk2(a1.x, a1.y), pk2(a1.z, a1.w));
    *(uint4*)aw1 = make_uint4(pk2(a2.x, a2.y), pk2(a2.z, a2.w), pk2(a3.x, a3.y), pk2(a3.z, a3.w));
    *(uint4*)bw0 = make_uint4(pk2(b0.x, b0.y), pk2(b0.z, b0.w), pk2(b1.x, b1.y), pk2(b1.z, b1.w));
    *(uint4*)bw1 = make_uint4(pk2(b2.x, b2.y), pk2(b2.z, b2.w), pk2(b3.x, b3.y), pk2(b3.z, b3.w));
    __syncthreads();
    short8 af2[4], bfr[4];
#pragma unroll
    for (int i = 0; i < 4; i++) {
      int arr = wr * 64 + i * 16 + rsel;
      af2[i] = *(const short8*)(aT + arr * 64 + ((slot ^ swz(arr)) << 4));
      int brr = wc * 64 + i * 16 + rsel;
      bfr[i] = *(const short8*)(bT + brr * 64 + ((slot ^ swz(brr)) << 4));
    }
#pragma unroll
    for (int mi = 0; mi < 4; mi++)
#pragma unroll
      for (int ni = 0; ni < 4; ni++)
        acc[mi][ni] = __builtin_amdgcn_mfma_f32_16x16x32_bf16(af2[mi], bfr[ni], acc[mi][ni], 0, 0, 0);
    __syncthreads();
  }
#pragma unroll
  for (int mi = 0; mi < 4; mi++) {
#pragma unroll
    for (int r = 0; r < 4; r++) {
      int rloc2 = wr * 64 + mi * 16 + slot * 4 + r;
      if (rloc2 < cnt) {
        size_t obase = (size_t)rl[rloc2] * NC;
#pragma unroll
        for (int ni = 0; ni < 4; ni++) {
          int col = nb * 128 + wc * 64 + ni * 16 + rsel;
          if (col < NC) out[obase + col] = acc[mi][ni][r] + bias[t * NC + col];
        }
      }
    }
  }
}

extern "C" void kernel_launch(void* const* d_in, const int* in_sizes, int n_in,
                              void* d_out, int out_size, void* d_ws, size_t ws_size,
                              hipStream_t stream) {
  const float* x = (const float*)d_in[0];
  const float* sigs = (const float*)d_in[1];
  const float* W = (const float*)d_in[2];
  const float* bias = (const float*)d_in[3];
  float* out = (float*)d_out;

  const size_t XBF_B = (size_t)NBROWS * ND * 2;    // 67,108,864
  const size_t WBF_B = (size_t)NT * 1024 * ND * 2; // 33,554,432
  bool fast = ws_size >= XBF_B + WBF_B + (1 << 20);

  char* wsb = (char*)d_ws;
  ushort_t* xbf = nullptr;
  ushort_t* wbf = nullptr;
  int* tidx;
  if (fast) {
    xbf = (ushort_t*)wsb;
    wbf = (ushort_t*)(wsb + XBF_B);
    tidx = (int*)(wsb + XBF_B + WBF_B);
  } else {
    tidx = (int*)wsb;
  }
  int* rowlist = tidx + NBROWS;
  int* meta = rowlist + NBROWS;
  int* blkhist = meta + 80;
  int* blkbase = blkhist + NHB * NT;

  fused_pre<<<8192, 512, 0, stream>>>(x, sigs, tidx, out + (size_t)NBROWS * NC, W, wbf, xbf);
  trix_hist<<<NHB, 256, 0, stream>>>(tidx, blkhist);
  trix_prefix<<<1, 256, 0, stream>>>(blkhist, blkbase, meta);
  trix_scatter<<<NHB, 256, 0, stream>>>(tidx, blkbase, rowlist);
  if (fast) {
    trix_gemm6<<<8 * MAX_RB128, 256, 0, stream>>>(xbf, wbf, bias, meta, rowlist, out);
  } else {
    trix_gemm_fb<<<dim3(8, MAX_RB128), 256, 0, stream>>>(x, W, bias, meta, rowlist, out);
  }
}

// Round 10
// 176.316 us; speedup vs baseline: 1.4280x; 1.0191x over previous
//
#include <hip/hip_runtime.h>

#define NBROWS 32768
#define ND 1024
#define NT 16
#define NC 1000
#define NHB 128
#define MAX_RB128 272  // worst-case 128-row blocks: 32768/128 + 16

typedef short short8 __attribute__((ext_vector_type(8)));
typedef float f32x4 __attribute__((ext_vector_type(4)));
typedef unsigned short ushort_t;

typedef __attribute__((address_space(1))) const unsigned int* gas_t;
typedef __attribute__((address_space(3))) unsigned int* las_t;

__device__ __forceinline__ void async_copy16(const void* g, void* l) {
  __builtin_amdgcn_global_load_lds((gas_t)g, (las_t)l, 16, 0, 0);
}

__device__ __forceinline__ unsigned f2bf(float f) {
  unsigned u = __float_as_uint(f);
  u += 0x7FFFu + ((u >> 16) & 1u);  // round-nearest-even
  return u >> 16;
}
__device__ __forceinline__ unsigned pk2(float a, float b) {
  return f2bf(a) | (f2bf(b) << 16);
}
__device__ __forceinline__ int swz(int row) { return (row & 3) ^ ((row >> 2) & 3); }

// ---------------- fused scores + x->bf16 + W-conversion ----------------
__global__ __launch_bounds__(512) void fused_pre(
    const float* __restrict__ x, const float* __restrict__ sigs_raw,
    int* __restrict__ tidx, float* __restrict__ out_idx,
    const float* __restrict__ W, ushort_t* __restrict__ wbf,
    ushort_t* __restrict__ xbf) {
  __shared__ signed char s_lds[NT * ND];
  int tid = threadIdx.x;
  int bid = blockIdx.x;
  if (bid >= 4096) {
    if (!wbf) return;
    size_t e = (((size_t)(bid - 4096)) * 512 + tid) * 8;
    int t = (int)(e >> 20);
    int rem = (int)(e & 1048575);
    int col = rem >> 10, k = rem & 1023;
    uint4 o;
    if (col < NC) {
      const float* src = W + ((size_t)t * NC + col) * ND + k;
      float4 a = *(const float4*)src;
      float4 b = *(const float4*)(src + 4);
      o = make_uint4(pk2(a.x, a.y), pk2(a.z, a.w), pk2(b.x, b.y), pk2(b.z, b.w));
    } else {
      o = make_uint4(0, 0, 0, 0);
    }
    *(uint4*)(wbf + e) = o;
    return;
  }
  for (int i = tid; i < NT * ND; i += 512) {
    float s = sigs_raw[i];
    s_lds[i] = (s > 0.3f) ? 1 : ((s < -0.3f) ? -1 : 0);
  }
  __syncthreads();
  int lane = tid & 63;
  int row = bid * 8 + (tid >> 6);
  const float* xr = x + (size_t)row * ND + lane * 16;
  float4 v0 = *(const float4*)(xr);
  float4 v1 = *(const float4*)(xr + 4);
  float4 v2 = *(const float4*)(xr + 8);
  float4 v3 = *(const float4*)(xr + 12);
  float xv[16] = {v0.x, v0.y, v0.z, v0.w, v1.x, v1.y, v1.z, v1.w,
                  v2.x, v2.y, v2.z, v2.w, v3.x, v3.y, v3.z, v3.w};
  if (xbf) {
    ushort_t* xo = xbf + (size_t)row * ND + lane * 16;
    *(uint4*)(xo) = make_uint4(pk2(v0.x, v0.y), pk2(v0.z, v0.w), pk2(v1.x, v1.y), pk2(v1.z, v1.w));
    *(uint4*)(xo + 8) = make_uint4(pk2(v2.x, v2.y), pk2(v2.z, v2.w), pk2(v3.x, v3.y), pk2(v3.z, v3.w));
  }
  float best = 0.0f;
  int bt = 0;
#pragma unroll
  for (int t = 0; t < NT; t++) {
    int4 sc = *(const int4*)(s_lds + t * ND + lane * 16);
    int wa[4] = {sc.x, sc.y, sc.z, sc.w};
    float p = 0.0f;
#pragma unroll
    for (int wi = 0; wi < 4; wi++)
#pragma unroll
      for (int bi = 0; bi < 4; bi++)
        p = fmaf((float)(signed char)(wa[wi] >> (8 * bi)), xv[wi * 4 + bi], p);
#pragma unroll
    for (int o = 32; o > 0; o >>= 1) p += __shfl_xor(p, o);
    if (t == 0 || p > best) { best = p; bt = t; }  // strict >: first index on tie (jnp.argmax)
  }
  if (lane == 0) {
    tidx[row] = bt;
    out_idx[row] = (float)bt;
  }
}

// ---------------- histogram / prefix / scatter (no global atomics) ----------------
__global__ __launch_bounds__(256) void trix_hist(const int* __restrict__ tidx,
                                                 int* __restrict__ blkhist) {
  __shared__ int h[NT];
  int tid = threadIdx.x;
  if (tid < NT) h[tid] = 0;
  __syncthreads();
  int t = tidx[blockIdx.x * 256 + tid];
  atomicAdd(&h[t], 1);
  __syncthreads();
  if (tid < NT) blkhist[blockIdx.x * NT + tid] = h[tid];
}

// meta: [0..15] counts, [16..32] row offsets, [50..66] cb128 (66=total)
__global__ __launch_bounds__(256) void trix_prefix(const int* __restrict__ blkhist,
                                                   int* __restrict__ blkbase,
                                                   int* __restrict__ meta) {
  __shared__ int part[NT][16];
  int tid = threadIdx.x;
  int t = tid >> 4, g = tid & 15;
  int s = 0;
  for (int b = g; b < NHB; b += 16) s += blkhist[b * NT + t];
  part[t][g] = s;
  __syncthreads();
  if (tid == 0) {
    int off = 0, cb2 = 0;
    for (int tt = 0; tt < NT; tt++) {
      int c = 0;
#pragma unroll
      for (int gg = 0; gg < 16; gg++) c += part[tt][gg];
      meta[tt] = c;
      meta[16 + tt] = off;
      meta[50 + tt] = cb2;
      off += c;
      cb2 += (c + 127) >> 7;
    }
    meta[32] = off;
    meta[66] = cb2;
  }
  __syncthreads();
  if (tid < NT) {
    int run = meta[16 + tid];
    for (int b = 0; b < NHB; b++) {
      blkbase[b * NT + tid] = run;
      run += blkhist[b * NT + tid];
    }
  }
}

__global__ __launch_bounds__(256) void trix_scatter(const int* __restrict__ tidx,
                                                    const int* __restrict__ blkbase,
                                                    int* __restrict__ rowlist) {
  __shared__ int h[NT];
  int tid = threadIdx.x;
  if (tid < NT) h[tid] = 0;
  __syncthreads();
  int row = blockIdx.x * 256 + tid;
  int t = tidx[row];
  int r = atomicAdd(&h[t], 1);
  rowlist[blkbase[blockIdx.x * NT + t] + r] = row;
}

// ---------------- GEMM: 128x128 tile, BK=64, single-buffer LDS with
// in-loop prefetch-under-MFMA pipeline: ds_read -> lgkm+bar -> STAGE(next)
// -> MFMA -> vmcnt(0)+bar. Gathered A from xbf, conflict-free chunk-XOR LDS.
__global__ __launch_bounds__(256, 3) void trix_gemm7(
    const ushort_t* __restrict__ xbf, const ushort_t* __restrict__ wbf,
    const float* __restrict__ bias, const int* __restrict__ meta,
    const int* __restrict__ rowlist, float* __restrict__ out) {
  __shared__ __align__(16) ushort_t A_lds[128 * 64];  // 16 KB: 128 rows x 64 k
  __shared__ __align__(16) ushort_t B_lds[128 * 64];  // 16 KB
  __shared__ int rl[128];
  int bid = blockIdx.x;
  int w = (bid & 7) * 272 + (bid >> 3);  // bijective XCD chunk swizzle: 2176 = 8*272
  int nb = w & 7, rb = w >> 3;           // each XCD owns 34 rb panels x all 8 nb
  if (rb >= meta[66]) return;
  int t = 0;
  while (t < NT - 1 && rb >= meta[51 + t]) t++;
  int row0 = meta[16 + t] + (rb - meta[50 + t]) * 128;
  int cnt = meta[17 + t] - row0;
  if (cnt > 128) cnt = 128;
  int tid = threadIdx.x;
  if (tid < 128) rl[tid] = rowlist[(tid < cnt) ? (row0 + tid) : row0];
  __syncthreads();

  int lane = tid & 63, wv = tid >> 6;
  // staging: wave wv covers rows [wv*32, wv*32+32) in 4 copies of 8 rows.
  // LDS[row][slot] holds global 16B-chunk (slot ^ (row&7)); dest linear (m104 rule).
  int srow = lane >> 3;                  // row%8 within copy
  int schunk = ((lane & 7) ^ srow) * 8;  // pre-swizzled source chunk (ushorts)
  const ushort_t* aS[4];
  const ushort_t* bS[4];
#pragma unroll
  for (int j = 0; j < 4; j++) {
    aS[j] = xbf + (size_t)rl[wv * 32 + j * 8 + srow] * ND + schunk;
    bS[j] = wbf + ((size_t)t << 20) + (size_t)(nb * 128 + wv * 32 + j * 8 + srow) * ND + schunk;
  }
  int ldst = wv * 2048 + lane * 8;  // wv*32*64 + lane*8 (ushorts), +j*512 per copy

  int wr = wv >> 1, wc = wv & 1;  // 2M x 2N waves; per-wave 64x64 output
  int rsel = lane & 15, ksl = lane >> 4, rx = rsel & 7;
  int sl0 = (ksl ^ rx) * 8;        // k-half 0: global chunk ksl
  int sl1 = ((4 + ksl) ^ rx) * 8;  // k-half 1: global chunk 4+ksl
  int aoff = (wr * 64 + rsel) * 64;
  int boff = (wc * 64 + rsel) * 64;

  f32x4 acc[4][4] = {};

#define STAGE(KTL)                                            \
  _Pragma("unroll") for (int j = 0; j < 4; j++) {             \
    async_copy16(aS[j] + (KTL) * 64, &A_lds[ldst + j * 512]); \
    async_copy16(bS[j] + (KTL) * 64, &B_lds[ldst + j * 512]); \
  }

  // prologue: stage k-tile 0; full drain
  STAGE(0);
  asm volatile("s_waitcnt vmcnt(0)" ::: "memory");
  __builtin_amdgcn_s_barrier();

#pragma unroll 1
  for (int kt = 0; kt < 16; ++kt) {
    // 1) sample LDS into registers (16 ds_read_b128)
    short8 af[4][2], bf2[4][2];
#pragma unroll
    for (int m = 0; m < 4; m++) {
      af[m][0] = *(const short8*)(&A_lds[aoff + m * 1024 + sl0]);
      af[m][1] = *(const short8*)(&A_lds[aoff + m * 1024 + sl1]);
    }
#pragma unroll
    for (int n = 0; n < 4; n++) {
      bf2[n][0] = *(const short8*)(&B_lds[boff + n * 1024 + sl0]);
      bf2[n][1] = *(const short8*)(&B_lds[boff + n * 1024 + sl1]);
    }
    // 2) all waves done reading -> safe to overwrite buffer
    asm volatile("s_waitcnt lgkmcnt(0)" ::: "memory");
    __builtin_amdgcn_sched_barrier(0);  // rule #18: pin MFMAs below the wait
    __builtin_amdgcn_s_barrier();
    // 3) prefetch next tile into the SAME buffer (flies under MFMA)
    if (kt < 15) STAGE(kt + 1);
    // 4) compute on registers
    __builtin_amdgcn_s_setprio(1);
#pragma unroll
    for (int n = 0; n < 4; n++)
#pragma unroll
      for (int m = 0; m < 4; m++) {
        acc[m][n] = __builtin_amdgcn_mfma_f32_16x16x32_bf16(af[m][0], bf2[n][0], acc[m][n], 0, 0, 0);
        acc[m][n] = __builtin_amdgcn_mfma_f32_16x16x32_bf16(af[m][1], bf2[n][1], acc[m][n], 0, 0, 0);
      }
    __builtin_amdgcn_s_setprio(0);
    // 5) own loads landed; barrier publishes to all waves
    asm volatile("s_waitcnt vmcnt(0)" ::: "memory");
    __builtin_amdgcn_s_barrier();
  }
#undef STAGE

  // epilogue: C/D layout col=lane&15, row=(lane>>4)*4+reg
  float bv[4];
  int bcol[4];
#pragma unroll
  for (int n = 0; n < 4; ++n) {
    bcol[n] = nb * 128 + wc * 64 + n * 16 + rsel;
    bv[n] = (bcol[n] < NC) ? bias[t * NC + bcol[n]] : 0.0f;
  }
#pragma unroll
  for (int m = 0; m < 4; ++m) {
#pragma unroll
    for (int r = 0; r < 4; ++r) {
      int lr = wr * 64 + m * 16 + ksl * 4 + r;
      if (lr < cnt) {
        size_t ob = (size_t)rl[lr] * NC;
#pragma unroll
        for (int n = 0; n < 4; ++n)
          if (bcol[n] < NC) out[ob + bcol[n]] = acc[m][n][r] + bv[n];
      }
    }
  }
}

// ---------------- fallback GEMM (f32 inputs, in-loop repack), cb128 meta ----------------
__global__ __launch_bounds__(256) void trix_gemm_fb(
    const float* __restrict__ x, const float* __restrict__ W,
    const float* __restrict__ bias, const int* __restrict__ meta,
    const int* __restrict__ rowlist, float* __restrict__ out) {
  __shared__ __align__(16) unsigned char aT[128 * 64];
  __shared__ __align__(16) unsigned char bT[128 * 64];
  __shared__ int rl[128];
  int nb = blockIdx.x, rb = blockIdx.y;
  if (rb >= meta[66]) return;
  int t = 0;
  while (t < NT - 1 && rb >= meta[51 + t]) t++;
  int row0 = meta[16 + t] + (rb - meta[50 + t]) * 128;
  int cnt = meta[17 + t] - row0;
  if (cnt > 128) cnt = 128;
  int tid = threadIdx.x;
  if (tid < 128) rl[tid] = rowlist[(tid < cnt) ? (row0 + tid) : row0];
  __syncthreads();
  int half = tid & 1, rloc = tid >> 1;
  const float* xp = x + (size_t)rl[rloc] * ND + half * 16;
  int wn = nb * 128 + rloc;
  if (wn > NC - 1) wn = NC - 1;
  const float* wp = W + ((size_t)t * NC + wn) * ND + half * 16;
  int sw = swz(rloc);
  unsigned char* aw0 = aT + rloc * 64 + (((half * 2 + 0) ^ sw) << 4);
  unsigned char* aw1 = aT + rloc * 64 + (((half * 2 + 1) ^ sw) << 4);
  unsigned char* bw0 = bT + rloc * 64 + (((half * 2 + 0) ^ sw) << 4);
  unsigned char* bw1 = bT + rloc * 64 + (((half * 2 + 1) ^ sw) << 4);
  int lane = tid & 63, wv = tid >> 6;
  int wr = wv >> 1, wc = wv & 1;
  int rsel = lane & 15, slot = lane >> 4;
  f32x4 acc[4][4] = {};
  for (int k0 = 0; k0 < ND; k0 += 32) {
    const float* xk = xp + k0;
    const float* wk = wp + k0;
    float4 a0 = *(const float4*)(xk);
    float4 a1 = *(const float4*)(xk + 4);
    float4 a2 = *(const float4*)(xk + 8);
    float4 a3 = *(const float4*)(xk + 12);
    float4 b0 = *(const float4*)(wk);
    float4 b1 = *(const float4*)(wk + 4);
    float4 b2 = *(const float4*)(wk + 8);
    float4 b3 = *(const float4*)(wk + 12);
    *(uint4*)aw0 = make_uint4(pk2(a0.x, a0.y), pk2(a0.z, a0.w), pk2(a1.x, a1.y), pk2(a1.z, a1.w));
    *(uint4*)aw1 = make_uint4(pk2(a2.x, a2.y), pk2(a2.z, a2.w), pk2(a3.x, a3.y), pk2(a3.z, a3.w));
    *(uint4*)bw0 = make_uint4(pk2(b0.x, b0.y), pk2(b0.z, b0.w), pk2(b1.x, b1.y), pk2(b1.z, b1.w));
    *(uint4*)bw1 = make_uint4(pk2(b2.x, b2.y), pk2(b2.z, b2.w), pk2(b3.x, b3.y), pk2(b3.z, b3.w));
    __syncthreads();
    short8 af2[4], bfr[4];
#pragma unroll
    for (int i = 0; i < 4; i++) {
      int arr = wr * 64 + i * 16 + rsel;
      af2[i] = *(const short8*)(aT + arr * 64 + ((slot ^ swz(arr)) << 4));
      int brr = wc * 64 + i * 16 + rsel;
      bfr[i] = *(const short8*)(bT + brr * 64 + ((slot ^ swz(brr)) << 4));
    }
#pragma unroll
    for (int mi = 0; mi < 4; mi++)
#pragma unroll
      for (int ni = 0; ni < 4; ni++)
        acc[mi][ni] = __builtin_amdgcn_mfma_f32_16x16x32_bf16(af2[mi], bfr[ni], acc[mi][ni], 0, 0, 0);
    __syncthreads();
  }
#pragma unroll
  for (int mi = 0; mi < 4; mi++) {
#pragma unroll
    for (int r = 0; r < 4; r++) {
      int rloc2 = wr * 64 + mi * 16 + slot * 4 + r;
      if (rloc2 < cnt) {
        size_t obase = (size_t)rl[rloc2] * NC;
#pragma unroll
        for (int ni = 0; ni < 4; ni++) {
          int col = nb * 128 + wc * 64 + ni * 16 + rsel;
          if (col < NC) out[obase + col] = acc[mi][ni][r] + bias[t * NC + col];
        }
      }
    }
  }
}

extern "C" void kernel_launch(void* const* d_in, const int* in_sizes, int n_in,
                              void* d_out, int out_size, void* d_ws, size_t ws_size,
                              hipStream_t stream) {
  const float* x = (const float*)d_in[0];
  const float* sigs = (const float*)d_in[1];
  const float* W = (const float*)d_in[2];
  const float* bias = (const float*)d_in[3];
  float* out = (float*)d_out;

  const size_t XBF_B = (size_t)NBROWS * ND * 2;    // 67,108,864
  const size_t WBF_B = (size_t)NT * 1024 * ND * 2; // 33,554,432
  bool fast = ws_size >= XBF_B + WBF_B + (1 << 20);

  char* wsb = (char*)d_ws;
  ushort_t* xbf = nullptr;
  ushort_t* wbf = nullptr;
  int* tidx;
  if (fast) {
    xbf = (ushort_t*)wsb;
    wbf = (ushort_t*)(wsb + XBF_B);
    tidx = (int*)(wsb + XBF_B + WBF_B);
  } else {
    tidx = (int*)wsb;
  }
  int* rowlist = tidx + NBROWS;
  int* meta = rowlist + NBROWS;
  int* blkhist = meta + 80;
  int* blkbase = blkhist + NHB * NT;

  fused_pre<<<8192, 512, 0, stream>>>(x, sigs, tidx, out + (size_t)NBROWS * NC, W, wbf, xbf);
  trix_hist<<<NHB, 256, 0, stream>>>(tidx, blkhist);
  trix_prefix<<<1, 256, 0, stream>>>(blkhist, blkbase, meta);
  trix_scatter<<<NHB, 256, 0, stream>>>(tidx, blkbase, rowlist);
  if (fast) {
    trix_gemm7<<<8 * MAX_RB128, 256, 0, stream>>>(xbf, wbf, bias, meta, rowlist, out);
  } else {
    trix_gemm_fb<<<dim3(8, MAX_RB128), 256, 0, stream>>>(x, W, bias, meta, rowlist, out);
  }
}